// Round 16
// baseline (1282.107 us; speedup 1.0000x reference)
//
#include <hip/hip_runtime.h>
#include <cstddef>
#include <cstdint>

#define D_MODEL 256
#define NHEAD   8
#define NLAYER  6
#define BATCH   4
#define QTOT    5440
#define MTOT    (BATCH*QTOT)   // 21760 = 170*128
#define DFFN    1024

typedef short  bf16x8 __attribute__((ext_vector_type(8)));
typedef float  f32x4  __attribute__((ext_vector_type(4)));
typedef unsigned short u16;

typedef __attribute__((address_space(1))) const void g_as1;
typedef __attribute__((address_space(3))) void l_as3;

__device__ __forceinline__ u16 f2bf(float f) {
    uint32_t u = __float_as_uint(f);
    return (u16)((u + 0x7fffu + ((u >> 16) & 1u)) >> 16);
}
__device__ __forceinline__ float bf2f(u16 s) {
    return __uint_as_float(((uint32_t)s) << 16);
}
__device__ __forceinline__ float bflo(uint32_t w) {
    return __uint_as_float(w << 16);
}
__device__ __forceinline__ float bfhi(uint32_t w) {
    return __uint_as_float(w & 0xFFFF0000u);
}

// Bijective XCD-aware swizzle (m204): maps linear bid -> tile id g so each
// XCD (bid%8) owns a contiguous chunk of g.
__device__ __forceinline__ int xcd_remap(int bid, int nwg) {
    int xcd = bid & 7, slot = bid >> 3;
    int q = nwg >> 3, r = nwg & 7;
    return (xcd < r ? xcd * (q + 1) : r * (q + 1) + (xcd - r) * q) + slot;
}

// ---------------------------------------------------------------------------
// FUSED flatten: all 4 levels, src+pos in one pass.
// ---------------------------------------------------------------------------
__global__ __launch_bounds__(256) void flatten_all(
    const float* __restrict__ s0, const float* __restrict__ s1,
    const float* __restrict__ s2, const float* __restrict__ s3,
    const float* __restrict__ p0, const float* __restrict__ p1,
    const float* __restrict__ p2, const float* __restrict__ p3,
    const float* __restrict__ lvl, float* __restrict__ posf,
    u16* __restrict__ oh, u16* __restrict__ ol,
    u16* __restrict__ qh, u16* __restrict__ ql)
{
    __shared__ float ts[32][33];
    __shared__ float tp[32][33];
    int bx = blockIdx.x;
    int l, hw0, qoff, HW;
    if (bx < 128)      { l = 0; hw0 = bx * 32;         qoff = 0;    HW = 4096; }
    else if (bx < 160) { l = 1; hw0 = (bx - 128) * 32; qoff = 4096; HW = 1024; }
    else if (bx < 168) { l = 2; hw0 = (bx - 160) * 32; qoff = 5120; HW = 256;  }
    else               { l = 3; hw0 = (bx - 168) * 32; qoff = 5376; HW = 64;   }
    const float* src = (l == 0) ? s0 : (l == 1) ? s1 : (l == 2) ? s2 : s3;
    const float* pos = (l == 0) ? p0 : (l == 1) ? p1 : (l == 2) ? p2 : p3;
    int tx = threadIdx.x, ty = threadIdx.y;
    int d0 = blockIdx.y * 32, b = blockIdx.z;
    const float* sp = src + (size_t)b * D_MODEL * HW;
    const float* pp = pos + (size_t)b * D_MODEL * HW;
#pragma unroll
    for (int j = 0; j < 4; ++j) {
        size_t off = (size_t)(d0 + ty + j * 8) * HW + hw0 + tx;
        ts[ty + j * 8][tx] = sp[off];
        tp[ty + j * 8][tx] = pp[off];
    }
    __syncthreads();
    float emb = lvl[l * D_MODEL + d0 + tx];
#pragma unroll
    for (int j = 0; j < 4; ++j) {
        int hw = ty + j * 8;
        float v = ts[tx][hw];
        float pv = tp[tx][hw] + emb;
        size_t idx = ((size_t)b * QTOT + qoff + hw0 + hw) * D_MODEL + d0 + tx;
        posf[idx] = pv;
        u16 h = f2bf(v);
        oh[idx] = h; ol[idx] = f2bf(v - bf2f(h));
        float q = v + pv;
        u16 qhv = f2bf(q);
        qh[idx] = qhv; ql[idx] = f2bf(q - bf2f(qhv));
    }
}

// ---------------------------------------------------------------------------
// FUSED weight convert: all 6 weight types x 6 layers in one dispatch.
// ---------------------------------------------------------------------------
__global__ __launch_bounds__(256) void wconv_all(
    const float* __restrict__ Wv, const float* __restrict__ Wo,
    const float* __restrict__ Wa, const float* __restrict__ Wu,
    const float* __restrict__ Wf1, const float* __restrict__ Wf2,
    u16* __restrict__ wv_h, u16* __restrict__ wv_l,
    u16* __restrict__ wc_h, u16* __restrict__ wc_l,
    u16* __restrict__ wu_h, u16* __restrict__ wu_l,
    u16* __restrict__ wf1_h, u16* __restrict__ wf1_l,
    u16* __restrict__ wf2_h, u16* __restrict__ wf2_l)
{
    __shared__ float t[32][33];
    int id = blockIdx.x;
    int layer = id / 736, r = id - layer * 736;
    const float* W; u16* Hl; u16* Ll; int K, N, n0, k0;
    if (r < 64) {
        W = Wv + (size_t)layer * 65536;
        Hl = wv_h + (size_t)layer * 65536; Ll = wv_l + (size_t)layer * 65536;
        K = 256; N = 256; n0 = (r & 7) * 32; k0 = (r >> 3) * 32;
    } else if (r < 128) {
        r -= 64;
        W = Wo + (size_t)layer * 65536;
        Hl = wc_h + (size_t)layer * 98304; Ll = wc_l + (size_t)layer * 98304;
        K = 256; N = 256; n0 = (r & 7) * 32; k0 = (r >> 3) * 32;
    } else if (r < 160) {
        r -= 128;
        W = Wa + (size_t)layer * 32768;
        Hl = wc_h + (size_t)layer * 98304 + 65536;
        Ll = wc_l + (size_t)layer * 98304 + 65536;
        K = 256; N = 128; n0 = (r & 3) * 32; k0 = (r >> 2) * 32;
    } else if (r < 224) {
        r -= 160;
        W = Wu + (size_t)layer * 65536;
        Hl = wu_h + (size_t)layer * 65536; Ll = wu_l + (size_t)layer * 65536;
        K = 256; N = 256; n0 = (r & 7) * 32; k0 = (r >> 3) * 32;
    } else if (r < 480) {
        r -= 224;
        W = Wf1 + (size_t)layer * 262144;
        Hl = wf1_h + (size_t)layer * 262144; Ll = wf1_l + (size_t)layer * 262144;
        K = 256; N = 1024; n0 = (r & 31) * 32; k0 = (r >> 5) * 32;
    } else {
        r -= 480;
        W = Wf2 + (size_t)layer * 262144;
        Hl = wf2_h + (size_t)layer * 262144; Ll = wf2_l + (size_t)layer * 262144;
        K = 1024; N = 256; n0 = (r & 7) * 32; k0 = (r >> 3) * 32;
    }
    int tx = threadIdx.x, ty = threadIdx.y;
#pragma unroll
    for (int j = 0; j < 4; ++j)
        t[ty + j * 8][tx] = W[(size_t)(k0 + ty + j * 8) * N + n0 + tx];
    __syncthreads();
#pragma unroll
    for (int j = 0; j < 4; ++j) {
        float v = t[tx][ty + j * 8];
        int n = n0 + ty + j * 8, k = k0 + tx;
        u16 h = f2bf(v);
        Hl[(size_t)n * K + k] = h;
        Ll[(size_t)n * K + k] = f2bf(v - bf2f(h));
    }
}

// ---------------------------------------------------------------------------
// Shared GEMM body: BM=128 BN=128 BK=32; global_load_lds staging
// (Ahi|Bhi|Blo LDS), A-lo in registers (HASAL=1 -> 3-pass; 0 -> 2-pass).
// Expects `row0` and `col0` already defined in enclosing scope.
// ---------------------------------------------------------------------------
#define GEMM_BODY(AH, AL, BH, BL, KDIM, HASAL, BIAS_EXPR, STORE_STMT)          \
    __shared__ __align__(16) short lds[2 * 12288];  /* 2 x 24 KB */            \
    int tid  = threadIdx.x;                                                    \
    int lane = tid & 63, wid = tid >> 6;                                       \
    int wr = wid >> 1, wc = wid & 1;                                           \
    const u16* gsrc0 = (wid == 0) ? (AH) : (wid == 1) ? (BH) : (BL);           \
    int rbase = (wid == 0) ? row0 : col0;                                      \
    const u16* gsrc = gsrc0 + (size_t)(rbase + (lane >> 2)) * (KDIM)           \
                            + (((lane & 3) ^ ((lane >> 3) & 3)) * 8);          \
    auto issue = [&](int kt, short* buf) {                                     \
        if (wid < 3) {                                                         \
            char* lbase = (char*)buf + wid * 8192;                             \
            const u16* g = gsrc + kt * 32;                                     \
            _Pragma("unroll")                                                  \
            for (int j = 0; j < 8; ++j) {                                      \
                __builtin_amdgcn_global_load_lds(                              \
                    (g_as1*)(g + (size_t)j * 16 * (KDIM)),                     \
                    (l_as3*)(lbase + j * 1024), 16, 0, 0);                     \
            }                                                                  \
        }                                                                      \
    };                                                                         \
    int l15 = lane & 15, l4 = lane >> 4;                                       \
    const u16* alsrc = (HASAL) ? (AL) : (AH);                                  \
    const u16* alp0 = alsrc + (size_t)(row0 + wr * 64 + l15) * (KDIM) + l4 * 8;\
    const u16* alp1 = alp0 + (size_t)16 * (KDIM);                              \
    const u16* alp2 = alp0 + (size_t)32 * (KDIM);                              \
    const u16* alp3 = alp0 + (size_t)48 * (KDIM);                              \
    f32x4 acc[4][4];                                                           \
    _Pragma("unroll")                                                          \
    for (int i = 0; i < 4; ++i)                                                \
        _Pragma("unroll")                                                      \
        for (int j = 0; j < 4; ++j) acc[i][j] = (f32x4){0.f, 0.f, 0.f, 0.f};   \
    auto compute = [&](const short* buf,                                       \
                       bf16x8 al0, bf16x8 al1, bf16x8 al2, bf16x8 al3) {       \
        const char* Ahi = (const char*)buf;                                    \
        const char* Bhi = (const char*)(buf + 4096);                           \
        const char* Blo = (const char*)(buf + 8192);                           \
        bf16x8 bh[4], bl[4];                                                   \
        _Pragma("unroll")                                                      \
        for (int nc = 0; nc < 4; ++nc) {                                       \
            int col = wc * 64 + nc * 16 + l15;                                 \
            int byt = col * 64 + ((l4 ^ ((col >> 1) & 3)) * 16);               \
            bh[nc] = *(const bf16x8*)(Bhi + byt);                              \
            bl[nc] = *(const bf16x8*)(Blo + byt);                              \
        }                                                                      \
        _Pragma("unroll")                                                      \
        for (int mr = 0; mr < 4; ++mr) {                                       \
            int row = wr * 64 + mr * 16 + l15;                                 \
            int byt = row * 64 + ((l4 ^ ((row >> 1) & 3)) * 16);               \
            bf16x8 ah = *(const bf16x8*)(Ahi + byt);                           \
            bf16x8 al = (mr == 0) ? al0 : (mr == 1) ? al1                      \
                       : (mr == 2) ? al2 : al3;                                \
            _Pragma("unroll")                                                  \
            for (int nc = 0; nc < 4; ++nc) {                                   \
                acc[mr][nc] = __builtin_amdgcn_mfma_f32_16x16x32_bf16(ah, bh[nc], acc[mr][nc], 0, 0, 0); \
                acc[mr][nc] = __builtin_amdgcn_mfma_f32_16x16x32_bf16(ah, bl[nc], acc[mr][nc], 0, 0, 0); \
                if (HASAL)                                                     \
                    acc[mr][nc] = __builtin_amdgcn_mfma_f32_16x16x32_bf16(al, bh[nc], acc[mr][nc], 0, 0, 0); \
            }                                                                  \
        }                                                                      \
    };                                                                         \
    int nk = (KDIM) >> 5;                                                      \
    short* lds0 = lds;                                                         \
    short* lds1 = lds + 12288;                                                 \
    bf16x8 a0A{}, a1A{}, a2A{}, a3A{}, a0B{}, a1B{}, a2B{}, a3B{};             \
    issue(0, lds0);                                                            \
    if (HASAL) {                                                               \
        a0A = *(const bf16x8*)(alp0); a1A = *(const bf16x8*)(alp1);            \
        a2A = *(const bf16x8*)(alp2); a3A = *(const bf16x8*)(alp3);            \
    }                                                                          \
    __syncthreads();                                                           \
    for (int kt = 0; kt < nk; kt += 2) {                                       \
        if (kt + 1 < nk) {                                                     \
            issue(kt + 1, lds1);                                               \
            if (HASAL) {                                                       \
                const int o1 = (kt + 1) * 32;                                  \
                a0B = *(const bf16x8*)(alp0 + o1); a1B = *(const bf16x8*)(alp1 + o1); \
                a2B = *(const bf16x8*)(alp2 + o1); a3B = *(const bf16x8*)(alp3 + o1); \
            }                                                                  \
        }                                                                      \
        compute(lds0, a0A, a1A, a2A, a3A);                                     \
        __syncthreads();                                                       \
        if (kt + 1 < nk) {                                                     \
            if (kt + 2 < nk) {                                                 \
                issue(kt + 2, lds0);                                           \
                if (HASAL) {                                                   \
                    const int o2 = (kt + 2) * 32;                              \
                    a0A = *(const bf16x8*)(alp0 + o2); a1A = *(const bf16x8*)(alp1 + o2); \
                    a2A = *(const bf16x8*)(alp2 + o2); a3A = *(const bf16x8*)(alp3 + o2); \
                }                                                              \
            }                                                                  \
            compute(lds1, a0B, a1B, a2B, a3B);                                 \
            __syncthreads();                                                   \
        }                                                                      \
    }                                                                          \
    _Pragma("unroll")                                                          \
    for (int nc = 0; nc < 4; ++nc) {                                           \
        int col = col0 + wc * 64 + nc * 16 + l15;                              \
        float bv = (BIAS_EXPR);                                                \
        _Pragma("unroll")                                                      \
        for (int mr = 0; mr < 4; ++mr) {                                       \
            int row = row0 + wr * 64 + mr * 16 + l4 * 4;                       \
            _Pragma("unroll")                                                  \
            for (int r = 0; r < 4; ++r) {                                      \
                float v = acc[mr][nc][r] + bv;                                 \
                size_t idx = (size_t)(row + r) * N + col;                      \
                STORE_STMT;                                                    \
            }                                                                  \
        }                                                                      \
    }

// GEMM modes: 0 fp32 C; 1 pair+ReLU; 2 pair; 3 single bf16 + ReLU.
// 1-D grid, XCD-swizzled; tile decode col-fastest (nCB col blocks).
template<int CMODE, int HASAL>
__global__ __launch_bounds__(256, 3) void gemm_pre(
    const u16* __restrict__ Ah, const u16* __restrict__ Al,
    const u16* __restrict__ Bh, const u16* __restrict__ Bl,
    const float* __restrict__ bias, const float* __restrict__ bias2, int nsplit,
    float* __restrict__ Cf, u16* __restrict__ Ch, u16* __restrict__ Cl,
    int N, int K, int nCB)
{
    int g = xcd_remap(blockIdx.x, gridDim.x);
    int col0 = (g % nCB) * 128;
    int row0 = (g / nCB) * 128;
    GEMM_BODY(Ah, Al, Bh, Bl, K, HASAL,
        (col < nsplit) ? bias[col] : bias2[col - nsplit],
        {
            if (CMODE == 0) { Cf[idx] = v; }
            else if (CMODE == 3) {
                v = fmaxf(v, 0.f);
                Ch[idx] = f2bf(v);
            } else {
                if (CMODE == 1) v = fmaxf(v, 0.f);
                u16 h = f2bf(v);
                Ch[idx] = h;
                Cl[idx] = f2bf(v - bf2f(h));
            }
        })
}

// Fused val + offlog GEMM, 1-D grid of 850 blocks, XCD-swizzled.
// val written as SINGLE bf16 (fed to msda gathers); offlog fp32.
__global__ __launch_bounds__(256, 3) void gemm_vo(
    const u16* __restrict__ oh, const u16* __restrict__ ol,
    const u16* __restrict__ qh, const u16* __restrict__ ql,
    const u16* __restrict__ wvh, const u16* __restrict__ wvl,
    const u16* __restrict__ wch, const u16* __restrict__ wcl,
    const float* __restrict__ b_val, const float* __restrict__ b_off,
    const float* __restrict__ b_att,
    u16* __restrict__ val16, float* __restrict__ offlog)
{
    int g = xcd_remap(blockIdx.x, gridDim.x);
    int cg = g % 5;
    int row0 = (g / 5) * 128;
    bool isv = cg < 2;
    const u16* Ah = isv ? oh : qh;
    const u16* Al = isv ? ol : ql;
    const u16* Bh = isv ? wvh : wch;
    const u16* Bl = isv ? wvl : wcl;
    int N = isv ? 256 : 384;
    int col0 = isv ? cg * 128 : (cg - 2) * 128;
    GEMM_BODY(Ah, Al, Bh, Bl, 256, 1,
        isv ? b_val[col] : (col < 256 ? b_off[col] : b_att[col - 256]),
        {
            if (isv) val16[idx] = f2bf(v);
            else     offlog[idx] = v;
        })
}

// ---------------------------------------------------------------------------
// MSDA v5: bf16 value (8B gathers) + bit-trick conversion (1 VALU/float) +
// 4-way ILP accumulator chains. XCD-remapped blocks for L2 locality.
// ---------------------------------------------------------------------------
__global__ __launch_bounds__(256) void msda5(
    const u16* __restrict__ value, const float* __restrict__ offlog,
    u16* __restrict__ eh, u16* __restrict__ el)
{
    __shared__ float aw_lds[32][16];
    __shared__ __align__(16) float wts[32 * 17 * 4];
    __shared__ __align__(16) int   idxs[32 * 17 * 4];

    int tid = threadIdx.x;
    int m0 = xcd_remap(blockIdx.x, gridDim.x) * 4;

    if (tid < 32) {
        int m = m0 + (tid >> 3);
        const float* lg = offlog + (size_t)m * 384 + 256 + (tid & 7) * 16;
        float w[16]; float mx = -1e30f;
#pragma unroll
        for (int i = 0; i < 4; ++i) {
            float4 v = reinterpret_cast<const float4*>(lg)[i];
            w[4 * i] = v.x; w[4 * i + 1] = v.y; w[4 * i + 2] = v.z; w[4 * i + 3] = v.w;
        }
#pragma unroll
        for (int j = 0; j < 16; ++j) mx = fmaxf(mx, w[j]);
        float s = 0.f;
#pragma unroll
        for (int j = 0; j < 16; ++j) { w[j] = __expf(w[j] - mx); s += w[j]; }
        float rs = 1.f / s;
#pragma unroll
        for (int j = 0; j < 16; ++j) aw_lds[tid][j] = w[j] * rs;
    }
    __syncthreads();

#pragma unroll
    for (int pp = 0; pp < 2; ++pp) {
        int pi = tid + 256 * pp;
        int qi = pi >> 7, rem = pi & 127;
        int h = rem >> 4, j = rem & 15;
        int l = j >> 2;
        int m = m0 + qi;
        int b = m / QTOT, q = m - b * QTOT;
        int lq = (q < 4096) ? 0 : (q < 5120) ? 1 : (q < 5376) ? 2 : 3;
        int qbase = (lq == 0) ? 0 : (lq == 1) ? 4096 : (lq == 2) ? 5120 : 5376;
        int qrem = q - qbase;
        int shq = 6 - lq;
        int Wq = 1 << shq;
        int yq = qrem >> shq, xq = qrem & (Wq - 1);
        float invq = 1.0f / (float)Wq;
        float ref_x = (xq + 0.5f) * invq;
        float ref_y = (yq + 0.5f) * invq;
        int HW = 64 >> l;
        float fHW = (float)HW;
        float invl = 1.0f / fHW;
        int loff = (l == 0) ? 0 : (l == 1) ? 4096 : (l == 2) ? 5120 : 5376;
        float ox = offlog[(size_t)m * 384 + h * 32 + j * 2 + 0];
        float oy = offlog[(size_t)m * 384 + h * 32 + j * 2 + 1];
        float aw = aw_lds[qi * 8 + h][j];
        float x = (ref_x + ox * invl) * fHW - 0.5f;
        float y = (ref_y + oy * invl) * fHW - 0.5f;
        float x0f = floorf(x), y0f = floorf(y);
        int x0 = (int)x0f, y0 = (int)y0f;
        float wx = x - x0f, wy = y - y0f;
        float vx0 = (x0 >= 0 && x0 < HW) ? 1.f : 0.f;
        float vx1 = (x0 + 1 >= 0 && x0 + 1 < HW) ? 1.f : 0.f;
        float vy0 = (y0 >= 0 && y0 < HW) ? 1.f : 0.f;
        float vy1 = (y0 + 1 >= 0 && y0 + 1 < HW) ? 1.f : 0.f;
        float w00 = (1.f - wx) * (1.f - wy) * aw * vx0 * vy0;
        float w01 = wx * (1.f - wy) * aw * vx1 * vy0;
        float w10 = (1.f - wx) * wy * aw * vx0 * vy1;
        float w11 = wx * wy * aw * vx1 * vy1;
        int xc0 = min(max(x0, 0), HW - 1);
        int xc1 = min(max(x0 + 1, 0), HW - 1);
        int yc0 = min(max(y0, 0), HW - 1);
        int yc1 = min(max(y0 + 1, 0), HW - 1);
        int rbase = b * QTOT + loff;
        int i00 = (rbase + yc0 * HW + xc0) << 9;   // row * 512 bytes (bf16)
        int i01 = (rbase + yc0 * HW + xc1) << 9;
        int i10 = (rbase + yc1 * HW + xc0) << 9;
        int i11 = (rbase + yc1 * HW + xc1) << 9;
        int sl = (qi * 8 + h) * 17 + j;
        reinterpret_cast<float4*>(wts)[sl] = make_float4(w00, w01, w10, w11);
        reinterpret_cast<int4*>(idxs)[sl] = make_int4(i00, i01, i10, i11);
    }
    __syncthreads();

    int lane = tid & 63;
    int qi = tid >> 6, h = lane >> 3, c8 = lane & 7;
    int m = m0 + qi;
    const char* vb = (const char*)value + h * 64 + c8 * 8;
    int base = (qi * 8 + h) * 17;

    float A0 = 0.f, A1 = 0.f, A2 = 0.f, A3 = 0.f;
    float B0 = 0.f, B1 = 0.f, B2 = 0.f, B3 = 0.f;
    float C0 = 0.f, C1 = 0.f, C2 = 0.f, C3 = 0.f;
    float D0 = 0.f, D1 = 0.f, D2 = 0.f, D3 = 0.f;

    auto corner = [&](int sl, float& r0, float& r1, float& r2, float& r3) {
        float4 w = reinterpret_cast<const float4*>(wts)[sl];
        int4  ix = reinterpret_cast<const int4*>(idxs)[sl];
        uint2 v00 = *reinterpret_cast<const uint2*>(vb + ix.x);
        uint2 v01 = *reinterpret_cast<const uint2*>(vb + ix.y);
        uint2 v10 = *reinterpret_cast<const uint2*>(vb + ix.z);
        uint2 v11 = *reinterpret_cast<const uint2*>(vb + ix.w);
        r0 += w.x * bflo(v00.x) + w.y * bflo(v01.x) + w.z * bflo(v10.x) + w.w * bflo(v11.x);
        r1 += w.x * bfhi(v00.x) + w.y * bfhi(v01.x) + w.z * bfhi(v10.x) + w.w * bfhi(v11.x);
        r2 += w.x * bflo(v00.y) + w.y * bflo(v01.y) + w.z * bflo(v10.y) + w.w * bflo(v11.y);
        r3 += w.x * bfhi(v00.y) + w.y * bfhi(v01.y) + w.z * bfhi(v10.y) + w.w * bfhi(v11.y);
    };

#pragma unroll
    for (int j = 0; j < 16; j += 4) {
        corner(base + j + 0, A0, A1, A2, A3);
        corner(base + j + 1, B0, B1, B2, B3);
        corner(base + j + 2, C0, C1, C2, C3);
        corner(base + j + 3, D0, D1, D2, D3);
    }
    float a0 = (A0 + B0) + (C0 + D0);
    float a1 = (A1 + B1) + (C1 + D1);
    float a2 = (A2 + B2) + (C2 + D2);
    float a3 = (A3 + B3) + (C3 + D3);

    size_t oidx = (size_t)m * D_MODEL + h * 32 + c8 * 4;
    ushort4 hv, lv;
    hv.x = f2bf(a0); lv.x = f2bf(a0 - bf2f(hv.x));
    hv.y = f2bf(a1); lv.y = f2bf(a1 - bf2f(hv.y));
    hv.z = f2bf(a2); lv.z = f2bf(a2 - bf2f(hv.z));
    hv.w = f2bf(a3); lv.w = f2bf(a3 - bf2f(hv.w));
    *reinterpret_cast<ushort4*>(eh + oidx) = hv;
    *reinterpret_cast<ushort4*>(el + oidx) = lv;
}

// ---------------------------------------------------------------------------
// add+LN on pair-stored residual (4 rows/block, wave per row).
// TMODE 0: t fp32.  TMODE 1: t bf16 pair (th, tl).
// WRITEQ: also q = y + posf -> qh/ql.  WRITEF32: y -> f32out.
// ---------------------------------------------------------------------------
template<int TMODE, int WRITEQ, int WRITEF32>
__global__ __launch_bounds__(256) void add_ln_pair(
    const float* __restrict__ t, const u16* __restrict__ th,
    const u16* __restrict__ tl,
    const float* __restrict__ g, const float* __restrict__ beta,
    u16* __restrict__ oh, u16* __restrict__ ol,
    const float* __restrict__ posf, u16* __restrict__ qh, u16* __restrict__ ql,
    float* __restrict__ f32out)
{
    int row = blockIdx.x * 4 + (threadIdx.x >> 6);
    int lane = threadIdx.x & 63;
    size_t base = (size_t)row * D_MODEL + lane * 4;
    ushort4 hv = *reinterpret_cast<const ushort4*>(oh + base);
    ushort4 lv = *reinterpret_cast<const ushort4*>(ol + base);
    float t0, t1, t2, t3;
    if (TMODE == 0) {
        float4 tv = *reinterpret_cast<const float4*>(t + base);
        t0 = tv.x; t1 = tv.y; t2 = tv.z; t3 = tv.w;
    } else {
        ushort4 thv = *reinterpret_cast<const ushort4*>(th + base);
        ushort4 tlv = *reinterpret_cast<const ushort4*>(tl + base);
        t0 = bf2f(thv.x) + bf2f(tlv.x);
        t1 = bf2f(thv.y) + bf2f(tlv.y);
        t2 = bf2f(thv.z) + bf2f(tlv.z);
        t3 = bf2f(thv.w) + bf2f(tlv.w);
    }
    float v0 = bf2f(hv.x) + bf2f(lv.x) + t0;
    float v1 = bf2f(hv.y) + bf2f(lv.y) + t1;
    float v2 = bf2f(hv.z) + bf2f(lv.z) + t2;
    float v3 = bf2f(hv.w) + bf2f(lv.w) + t3;
    float s = v0 + v1 + v2 + v3;
#pragma unroll
    for (int o = 32; o > 0; o >>= 1) s += __shfl_xor(s, o);
    float mean = s * (1.f / D_MODEL);
    float d0 = v0 - mean, d1 = v1 - mean, d2 = v2 - mean, d3 = v3 - mean;
    float ss = d0 * d0 + d1 * d1 + d2 * d2 + d3 * d3;
#pragma unroll
    for (int o = 32; o > 0; o >>= 1) ss += __shfl_xor(ss, o);
    float rstd = rsqrtf(ss * (1.f / D_MODEL) + 1e-5f);
    float4 gv = *reinterpret_cast<const float4*>(&g[lane * 4]);
    float4 bv = *reinterpret_cast<const float4*>(&beta[lane * 4]);
    float y0 = d0 * rstd * gv.x + bv.x;
    float y1 = d1 * rstd * gv.y + bv.y;
    float y2 = d2 * rstd * gv.z + bv.z;
    float y3 = d3 * rstd * gv.w + bv.w;
    ushort4 nh, nl;
    nh.x = f2bf(y0); nl.x = f2bf(y0 - bf2f(nh.x));
    nh.y = f2bf(y1); nl.y = f2bf(y1 - bf2f(nh.y));
    nh.z = f2bf(y2); nl.z = f2bf(y2 - bf2f(nh.z));
    nh.w = f2bf(y3); nl.w = f2bf(y3 - bf2f(nh.w));
    *reinterpret_cast<ushort4*>(oh + base) = nh;
    *reinterpret_cast<ushort4*>(ol + base) = nl;
    if (WRITEQ) {
        float4 pv = *reinterpret_cast<const float4*>(posf + base);
        float q0 = y0 + pv.x, q1 = y1 + pv.y, q2 = y2 + pv.z, q3 = y3 + pv.w;
        ushort4 qhv, qlv;
        qhv.x = f2bf(q0); qlv.x = f2bf(q0 - bf2f(qhv.x));
        qhv.y = f2bf(q1); qlv.y = f2bf(q1 - bf2f(qhv.y));
        qhv.z = f2bf(q2); qlv.z = f2bf(q2 - bf2f(qhv.z));
        qhv.w = f2bf(q3); qlv.w = f2bf(q3 - bf2f(qhv.w));
        *reinterpret_cast<ushort4*>(qh + base) = qhv;
        *reinterpret_cast<ushort4*>(ql + base) = qlv;
    }
    if (WRITEF32) {
        *reinterpret_cast<float4*>(f32out + base) = make_float4(y0, y1, y2, y3);
    }
}

// ---------------------------------------------------------------------------
extern "C" void kernel_launch(void* const* d_in, const int* in_sizes, int n_in,
                              void* d_out, int out_size, void* d_ws, size_t ws_size,
                              hipStream_t stream)
{
    // dict order is INTERLEAVED: src0,pos0,src1,pos1,...
    const float* src[4] = {(const float*)d_in[0], (const float*)d_in[2],
                           (const float*)d_in[4], (const float*)d_in[6]};
    const float* pos[4] = {(const float*)d_in[1], (const float*)d_in[3],
                           (const float*)d_in[5], (const float*)d_in[7]};
    const float* lvl   = (const float*)d_in[8];
    const float* W_off = (const float*)d_in[9];
    const float* b_off = (const float*)d_in[10];
    const float* W_att = (const float*)d_in[11];
    const float* b_att = (const float*)d_in[12];
    const float* W_val = (const float*)d_in[13];
    const float* b_val = (const float*)d_in[14];
    const float* W_out = (const float*)d_in[15];
    const float* b_out = (const float*)d_in[16];
    const float* ln1g  = (const float*)d_in[17];
    const float* ln1b  = (const float*)d_in[18];
    const float* W_ff1 = (const float*)d_in[19];
    const float* b_ff1 = (const float*)d_in[20];
    const float* W_ff2 = (const float*)d_in[21];
    const float* b_ff2 = (const float*)d_in[22];
    const float* ln2g  = (const float*)d_in[23];
    const float* ln2b  = (const float*)d_in[24];

    float* ws = (float*)d_ws;
    const size_t MD = (size_t)MTOT * D_MODEL;    // 5,570,560

    // Workspace layout (~140.6 MB; proven to fit in rounds 4-15):
    float* posf = ws;                                    // fp32 [M,256]
    u16* oh = (u16*)(ws + MD);
    u16* ol = oh + MD;
    u16* qh = ol + MD;                                   // q / e / ff2-out pair
    u16* ql = qh + MD;
    u16* eh = qh; u16* el = ql;
    float* val    = (float*)(ql + MD);                   // region: val16 / hid
    float* offlog = val + MD;                            // fp32 [M,384]; tmp
    float* tmp    = offlog;
    u16* val16 = (u16*)val;      // single-bf16 value [M,256] (msda input)
    u16* hid = (u16*)val;        // FFN hidden bf16 [M,1024] (val16 dead then)
    u16* wb = (u16*)(offlog + (size_t)MTOT * 384);
    size_t o = 0;
    u16* wv_h = wb + o; o += 6 * 65536;  u16* wv_l = wb + o; o += 6 * 65536;
    u16* wc_h = wb + o; o += 6 * 98304;  u16* wc_l = wb + o; o += 6 * 98304;
    u16* wu_h = wb + o; o += 6 * 65536;  u16* wu_l = wb + o; o += 6 * 65536;
    u16* wf1_h = wb + o; o += 6 * 262144; u16* wf1_l = wb + o; o += 6 * 262144;
    u16* wf2_h = wb + o; o += 6 * 262144; u16* wf2_l = wb + o; o += 6 * 262144;

    dim3 cb(32, 8);
    flatten_all<<<dim3(170, 8, BATCH), cb, 0, stream>>>(
        src[0], src[1], src[2], src[3], pos[0], pos[1], pos[2], pos[3],
        lvl, posf, oh, ol, qh, ql);
    wconv_all<<<6 * 736, cb, 0, stream>>>(
        W_val, W_off, W_att, W_out, W_ff1, W_ff2,
        wv_h, wv_l, wc_h, wc_l, wu_h, wu_l, wf1_h, wf1_l, wf2_h, wf2_l);

    for (int i = 0; i < NLAYER; ++i) {
        gemm_vo<<<850, 256, 0, stream>>>(
            oh, ol, qh, ql,
            wv_h + i * 65536, wv_l + i * 65536,
            wc_h + i * 98304, wc_l + i * 98304,
            b_val + i * 256, b_off + i * 256, b_att + i * 128,
            val16, offlog);
        msda5<<<MTOT / 4, 256, 0, stream>>>(val16, offlog, eh, el);
        gemm_pre<0, 1><<<340, 256, 0, stream>>>(
            eh, el, wu_h + i * 65536, wu_l + i * 65536,
            b_out + i * 256, b_out + i * 256, 256,
            tmp, nullptr, nullptr, 256, 256, 2);
        add_ln_pair<0, 0, 0><<<MTOT / 4, 256, 0, stream>>>(
            tmp, nullptr, nullptr, ln1g + i * 256, ln1b + i * 256, oh, ol,
            nullptr, nullptr, nullptr, nullptr);
        // FFN full-M: ff1 -> single-bf16 hidden; ff2 2-pass (no A-lo).
        gemm_pre<3, 1><<<1360, 256, 0, stream>>>(
            oh, ol, wf1_h + i * 262144, wf1_l + i * 262144,
            b_ff1 + i * 1024, b_ff1 + i * 1024, 1024,
            nullptr, hid, nullptr, 1024, 256, 8);
        gemm_pre<2, 0><<<340, 256, 0, stream>>>(
            hid, nullptr, wf2_h + i * 262144, wf2_l + i * 262144,
            b_ff2 + i * 256, b_ff2 + i * 256, 256,
            nullptr, eh, el, 256, 1024, 2);
        if (i < NLAYER - 1)
            add_ln_pair<1, 1, 0><<<MTOT / 4, 256, 0, stream>>>(
                nullptr, eh, el, ln2g + i * 256, ln2b + i * 256, oh, ol,
                posf, qh, ql, nullptr);
        else
            add_ln_pair<1, 0, 1><<<MTOT / 4, 256, 0, stream>>>(
                nullptr, eh, el, ln2g + i * 256, ln2b + i * 256, oh, ol,
                nullptr, nullptr, nullptr, (float*)d_out);
    }
    (void)in_sizes; (void)n_in; (void)out_size; (void)ws_size;
}

// Round 17
// 1246.106 us; speedup vs baseline: 1.0289x; 1.0289x over previous
//
#include <hip/hip_runtime.h>
#include <cstddef>
#include <cstdint>

#define D_MODEL 256
#define NHEAD   8
#define NLAYER  6
#define BATCH   4
#define QTOT    5440
#define MTOT    (BATCH*QTOT)   // 21760 = 170*128
#define DFFN    1024

typedef short  bf16x8 __attribute__((ext_vector_type(8)));
typedef float  f32x4  __attribute__((ext_vector_type(4)));
typedef unsigned short u16;

typedef __attribute__((address_space(1))) const void g_as1;
typedef __attribute__((address_space(3))) void l_as3;

__device__ __forceinline__ u16 f2bf(float f) {
    uint32_t u = __float_as_uint(f);
    return (u16)((u + 0x7fffu + ((u >> 16) & 1u)) >> 16);
}
__device__ __forceinline__ float bf2f(u16 s) {
    return __uint_as_float(((uint32_t)s) << 16);
}

// Bijective XCD-aware swizzle (m204): maps linear bid -> tile id g so each
// XCD (bid%8) owns a contiguous chunk of g; with col-fastest tile decode,
// one row panel's col-blocks land on the same XCD's L2.
__device__ __forceinline__ int xcd_remap(int bid, int nwg) {
    int xcd = bid & 7, slot = bid >> 3;
    int q = nwg >> 3, r = nwg & 7;
    return (xcd < r ? xcd * (q + 1) : r * (q + 1) + (xcd - r) * q) + slot;
}

// ---------------------------------------------------------------------------
// FUSED flatten: all 4 levels, src+pos in one pass.
// Writes posf (fp32), oh/ol (out pair), qh/ql (q pair).
// ---------------------------------------------------------------------------
__global__ __launch_bounds__(256) void flatten_all(
    const float* __restrict__ s0, const float* __restrict__ s1,
    const float* __restrict__ s2, const float* __restrict__ s3,
    const float* __restrict__ p0, const float* __restrict__ p1,
    const float* __restrict__ p2, const float* __restrict__ p3,
    const float* __restrict__ lvl, float* __restrict__ posf,
    u16* __restrict__ oh, u16* __restrict__ ol,
    u16* __restrict__ qh, u16* __restrict__ ql)
{
    __shared__ float ts[32][33];
    __shared__ float tp[32][33];
    int bx = blockIdx.x;
    int l, hw0, qoff, HW;
    if (bx < 128)      { l = 0; hw0 = bx * 32;         qoff = 0;    HW = 4096; }
    else if (bx < 160) { l = 1; hw0 = (bx - 128) * 32; qoff = 4096; HW = 1024; }
    else if (bx < 168) { l = 2; hw0 = (bx - 160) * 32; qoff = 5120; HW = 256;  }
    else               { l = 3; hw0 = (bx - 168) * 32; qoff = 5376; HW = 64;   }
    const float* src = (l == 0) ? s0 : (l == 1) ? s1 : (l == 2) ? s2 : s3;
    const float* pos = (l == 0) ? p0 : (l == 1) ? p1 : (l == 2) ? p2 : p3;
    int tx = threadIdx.x, ty = threadIdx.y;
    int d0 = blockIdx.y * 32, b = blockIdx.z;
    const float* sp = src + (size_t)b * D_MODEL * HW;
    const float* pp = pos + (size_t)b * D_MODEL * HW;
#pragma unroll
    for (int j = 0; j < 4; ++j) {
        size_t off = (size_t)(d0 + ty + j * 8) * HW + hw0 + tx;
        ts[ty + j * 8][tx] = sp[off];
        tp[ty + j * 8][tx] = pp[off];
    }
    __syncthreads();
    float emb = lvl[l * D_MODEL + d0 + tx];
#pragma unroll
    for (int j = 0; j < 4; ++j) {
        int hw = ty + j * 8;
        float v = ts[tx][hw];
        float pv = tp[tx][hw] + emb;
        size_t idx = ((size_t)b * QTOT + qoff + hw0 + hw) * D_MODEL + d0 + tx;
        posf[idx] = pv;
        u16 h = f2bf(v);
        oh[idx] = h; ol[idx] = f2bf(v - bf2f(h));
        float q = v + pv;
        u16 qhv = f2bf(q);
        qh[idx] = qhv; ql[idx] = f2bf(q - bf2f(qhv));
    }
}

// ---------------------------------------------------------------------------
// FUSED weight convert: all 6 weight types x 6 layers in one dispatch.
// W fp32 [L][K][N] -> hi/lo bf16 [L][N][K].
// ---------------------------------------------------------------------------
__global__ __launch_bounds__(256) void wconv_all(
    const float* __restrict__ Wv, const float* __restrict__ Wo,
    const float* __restrict__ Wa, const float* __restrict__ Wu,
    const float* __restrict__ Wf1, const float* __restrict__ Wf2,
    u16* __restrict__ wv_h, u16* __restrict__ wv_l,
    u16* __restrict__ wc_h, u16* __restrict__ wc_l,
    u16* __restrict__ wu_h, u16* __restrict__ wu_l,
    u16* __restrict__ wf1_h, u16* __restrict__ wf1_l,
    u16* __restrict__ wf2_h, u16* __restrict__ wf2_l)
{
    __shared__ float t[32][33];
    int id = blockIdx.x;
    int layer = id / 736, r = id - layer * 736;
    const float* W; u16* Hl; u16* Ll; int K, N, n0, k0;
    if (r < 64) {
        W = Wv + (size_t)layer * 65536;
        Hl = wv_h + (size_t)layer * 65536; Ll = wv_l + (size_t)layer * 65536;
        K = 256; N = 256; n0 = (r & 7) * 32; k0 = (r >> 3) * 32;
    } else if (r < 128) {
        r -= 64;
        W = Wo + (size_t)layer * 65536;
        Hl = wc_h + (size_t)layer * 98304; Ll = wc_l + (size_t)layer * 98304;
        K = 256; N = 256; n0 = (r & 7) * 32; k0 = (r >> 3) * 32;
    } else if (r < 160) {
        r -= 128;
        W = Wa + (size_t)layer * 32768;
        Hl = wc_h + (size_t)layer * 98304 + 65536;
        Ll = wc_l + (size_t)layer * 98304 + 65536;
        K = 256; N = 128; n0 = (r & 3) * 32; k0 = (r >> 2) * 32;
    } else if (r < 224) {
        r -= 160;
        W = Wu + (size_t)layer * 65536;
        Hl = wu_h + (size_t)layer * 65536; Ll = wu_l + (size_t)layer * 65536;
        K = 256; N = 256; n0 = (r & 7) * 32; k0 = (r >> 3) * 32;
    } else if (r < 480) {
        r -= 224;
        W = Wf1 + (size_t)layer * 262144;
        Hl = wf1_h + (size_t)layer * 262144; Ll = wf1_l + (size_t)layer * 262144;
        K = 256; N = 1024; n0 = (r & 31) * 32; k0 = (r >> 5) * 32;
    } else {
        r -= 480;
        W = Wf2 + (size_t)layer * 262144;
        Hl = wf2_h + (size_t)layer * 262144; Ll = wf2_l + (size_t)layer * 262144;
        K = 1024; N = 256; n0 = (r & 7) * 32; k0 = (r >> 3) * 32;
    }
    int tx = threadIdx.x, ty = threadIdx.y;
#pragma unroll
    for (int j = 0; j < 4; ++j)
        t[ty + j * 8][tx] = W[(size_t)(k0 + ty + j * 8) * N + n0 + tx];
    __syncthreads();
#pragma unroll
    for (int j = 0; j < 4; ++j) {
        float v = t[tx][ty + j * 8];
        int n = n0 + ty + j * 8, k = k0 + tx;
        u16 h = f2bf(v);
        Hl[(size_t)n * K + k] = h;
        Ll[(size_t)n * K + k] = f2bf(v - bf2f(h));
    }
}

// ---------------------------------------------------------------------------
// Shared GEMM body: BM=128 BN=128 BK=32; global_load_lds staging
// (Ahi|Bhi|Blo LDS), A-lo in registers (HASAL=1 -> 3-pass; 0 -> 2-pass).
// Expects `row0` and `col0` already defined in enclosing scope.
// ---------------------------------------------------------------------------
#define GEMM_BODY(AH, AL, BH, BL, KDIM, HASAL, BIAS_EXPR, STORE_STMT)          \
    __shared__ __align__(16) short lds[2 * 12288];  /* 2 x 24 KB */            \
    int tid  = threadIdx.x;                                                    \
    int lane = tid & 63, wid = tid >> 6;                                       \
    int wr = wid >> 1, wc = wid & 1;                                           \
    const u16* gsrc0 = (wid == 0) ? (AH) : (wid == 1) ? (BH) : (BL);           \
    int rbase = (wid == 0) ? row0 : col0;                                      \
    const u16* gsrc = gsrc0 + (size_t)(rbase + (lane >> 2)) * (KDIM)           \
                            + (((lane & 3) ^ ((lane >> 3) & 3)) * 8);          \
    auto issue = [&](int kt, short* buf) {                                     \
        if (wid < 3) {                                                         \
            char* lbase = (char*)buf + wid * 8192;                             \
            const u16* g = gsrc + kt * 32;                                     \
            _Pragma("unroll")                                                  \
            for (int j = 0; j < 8; ++j) {                                      \
                __builtin_amdgcn_global_load_lds(                              \
                    (g_as1*)(g + (size_t)j * 16 * (KDIM)),                     \
                    (l_as3*)(lbase + j * 1024), 16, 0, 0);                     \
            }                                                                  \
        }                                                                      \
    };                                                                         \
    int l15 = lane & 15, l4 = lane >> 4;                                       \
    const u16* alsrc = (HASAL) ? (AL) : (AH);                                  \
    const u16* alp0 = alsrc + (size_t)(row0 + wr * 64 + l15) * (KDIM) + l4 * 8;\
    const u16* alp1 = alp0 + (size_t)16 * (KDIM);                              \
    const u16* alp2 = alp0 + (size_t)32 * (KDIM);                              \
    const u16* alp3 = alp0 + (size_t)48 * (KDIM);                              \
    f32x4 acc[4][4];                                                           \
    _Pragma("unroll")                                                          \
    for (int i = 0; i < 4; ++i)                                                \
        _Pragma("unroll")                                                      \
        for (int j = 0; j < 4; ++j) acc[i][j] = (f32x4){0.f, 0.f, 0.f, 0.f};   \
    auto compute = [&](const short* buf,                                       \
                       bf16x8 al0, bf16x8 al1, bf16x8 al2, bf16x8 al3) {       \
        const char* Ahi = (const char*)buf;                                    \
        const char* Bhi = (const char*)(buf + 4096);                           \
        const char* Blo = (const char*)(buf + 8192);                           \
        bf16x8 bh[4], bl[4];                                                   \
        _Pragma("unroll")                                                      \
        for (int nc = 0; nc < 4; ++nc) {                                       \
            int col = wc * 64 + nc * 16 + l15;                                 \
            int byt = col * 64 + ((l4 ^ ((col >> 1) & 3)) * 16);               \
            bh[nc] = *(const bf16x8*)(Bhi + byt);                              \
            bl[nc] = *(const bf16x8*)(Blo + byt);                              \
        }                                                                      \
        _Pragma("unroll")                                                      \
        for (int mr = 0; mr < 4; ++mr) {                                       \
            int row = wr * 64 + mr * 16 + l15;                                 \
            int byt = row * 64 + ((l4 ^ ((row >> 1) & 3)) * 16);               \
            bf16x8 ah = *(const bf16x8*)(Ahi + byt);                           \
            bf16x8 al = (mr == 0) ? al0 : (mr == 1) ? al1                      \
                       : (mr == 2) ? al2 : al3;                                \
            _Pragma("unroll")                                                  \
            for (int nc = 0; nc < 4; ++nc) {                                   \
                acc[mr][nc] = __builtin_amdgcn_mfma_f32_16x16x32_bf16(ah, bh[nc], acc[mr][nc], 0, 0, 0); \
                acc[mr][nc] = __builtin_amdgcn_mfma_f32_16x16x32_bf16(ah, bl[nc], acc[mr][nc], 0, 0, 0); \
                if (HASAL)                                                     \
                    acc[mr][nc] = __builtin_amdgcn_mfma_f32_16x16x32_bf16(al, bh[nc], acc[mr][nc], 0, 0, 0); \
            }                                                                  \
        }                                                                      \
    };                                                                         \
    int nk = (KDIM) >> 5;                                                      \
    short* lds0 = lds;                                                         \
    short* lds1 = lds + 12288;                                                 \
    bf16x8 a0A{}, a1A{}, a2A{}, a3A{}, a0B{}, a1B{}, a2B{}, a3B{};             \
    issue(0, lds0);                                                            \
    if (HASAL) {                                                               \
        a0A = *(const bf16x8*)(alp0); a1A = *(const bf16x8*)(alp1);            \
        a2A = *(const bf16x8*)(alp2); a3A = *(const bf16x8*)(alp3);            \
    }                                                                          \
    __syncthreads();                                                           \
    for (int kt = 0; kt < nk; kt += 2) {                                       \
        if (kt + 1 < nk) {                                                     \
            issue(kt + 1, lds1);                                               \
            if (HASAL) {                                                       \
                const int o1 = (kt + 1) * 32;                                  \
                a0B = *(const bf16x8*)(alp0 + o1); a1B = *(const bf16x8*)(alp1 + o1); \
                a2B = *(const bf16x8*)(alp2 + o1); a3B = *(const bf16x8*)(alp3 + o1); \
            }                                                                  \
        }                                                                      \
        compute(lds0, a0A, a1A, a2A, a3A);                                     \
        __syncthreads();                                                       \
        if (kt + 1 < nk) {                                                     \
            if (kt + 2 < nk) {                                                 \
                issue(kt + 2, lds0);                                           \
                if (HASAL) {                                                   \
                    const int o2 = (kt + 2) * 32;                              \
                    a0A = *(const bf16x8*)(alp0 + o2); a1A = *(const bf16x8*)(alp1 + o2); \
                    a2A = *(const bf16x8*)(alp2 + o2); a3A = *(const bf16x8*)(alp3 + o2); \
                }                                                              \
            }                                                                  \
            compute(lds1, a0B, a1B, a2B, a3B);                                 \
            __syncthreads();                                                   \
        }                                                                      \
    }                                                                          \
    _Pragma("unroll")                                                          \
    for (int nc = 0; nc < 4; ++nc) {                                           \
        int col = col0 + wc * 64 + nc * 16 + l15;                              \
        float bv = (BIAS_EXPR);                                                \
        _Pragma("unroll")                                                      \
        for (int mr = 0; mr < 4; ++mr) {                                       \
            int row = row0 + wr * 64 + mr * 16 + l4 * 4;                       \
            _Pragma("unroll")                                                  \
            for (int r = 0; r < 4; ++r) {                                      \
                float v = acc[mr][nc][r] + bv;                                 \
                size_t idx = (size_t)(row + r) * N + col;                      \
                STORE_STMT;                                                    \
            }                                                                  \
        }                                                                      \
    }

// GEMM modes: 0 fp32 C; 1 pair+ReLU; 2 pair; 3 single bf16 + ReLU.
// 1-D grid, XCD-swizzled; tile decode col-fastest (nCB col blocks).
template<int CMODE, int HASAL>
__global__ __launch_bounds__(256, 3) void gemm_pre(
    const u16* __restrict__ Ah, const u16* __restrict__ Al,
    const u16* __restrict__ Bh, const u16* __restrict__ Bl,
    const float* __restrict__ bias, const float* __restrict__ bias2, int nsplit,
    float* __restrict__ Cf, u16* __restrict__ Ch, u16* __restrict__ Cl,
    int N, int K, int nCB)
{
    int g = xcd_remap(blockIdx.x, gridDim.x);
    int col0 = (g % nCB) * 128;
    int row0 = (g / nCB) * 128;
    GEMM_BODY(Ah, Al, Bh, Bl, K, HASAL,
        (col < nsplit) ? bias[col] : bias2[col - nsplit],
        {
            if (CMODE == 0) { Cf[idx] = v; }
            else if (CMODE == 3) {
                v = fmaxf(v, 0.f);
                Ch[idx] = f2bf(v);
            } else {
                if (CMODE == 1) v = fmaxf(v, 0.f);
                u16 h = f2bf(v);
                Ch[idx] = h;
                Cl[idx] = f2bf(v - bf2f(h));
            }
        })
}

// Fused val + offlog GEMM, 1-D grid of 850 blocks, XCD-swizzled.
// Tile decode: cg = g%5 (cg<2 -> val cols, cg>=2 -> offlog cols), row = g/5.
__global__ __launch_bounds__(256, 3) void gemm_vo(
    const u16* __restrict__ oh, const u16* __restrict__ ol,
    const u16* __restrict__ qh, const u16* __restrict__ ql,
    const u16* __restrict__ wvh, const u16* __restrict__ wvl,
    const u16* __restrict__ wch, const u16* __restrict__ wcl,
    const float* __restrict__ b_val, const float* __restrict__ b_off,
    const float* __restrict__ b_att,
    float* __restrict__ val, float* __restrict__ offlog)
{
    int g = xcd_remap(blockIdx.x, gridDim.x);
    int cg = g % 5;
    int row0 = (g / 5) * 128;
    bool isv = cg < 2;
    const u16* Ah = isv ? oh : qh;
    const u16* Al = isv ? ol : ql;
    const u16* Bh = isv ? wvh : wch;
    const u16* Bl = isv ? wvl : wcl;
    float* Cf = isv ? val : offlog;
    int N = isv ? 256 : 384;
    int col0 = isv ? cg * 128 : (cg - 2) * 128;
    GEMM_BODY(Ah, Al, Bh, Bl, 256, 1,
        isv ? b_val[col] : (col < 256 ? b_off[col] : b_att[col - 256]),
        { Cf[idx] = v; })
}

// ---------------------------------------------------------------------------
// MSDA v3b: LDS-shared weight precompute, gather phase with dual FMA chains.
// One block = 4 queries (one wave each); fused softmax; bf16-pair output.
// ---------------------------------------------------------------------------
__global__ __launch_bounds__(256) void msda3(
    const float* __restrict__ value, const float* __restrict__ offlog,
    u16* __restrict__ eh, u16* __restrict__ el)
{
    __shared__ float aw_lds[32][16];
    __shared__ __align__(16) float wts[32 * 17 * 4];
    __shared__ __align__(16) int   idxs[32 * 17 * 4];

    int tid = threadIdx.x;
    int m0 = blockIdx.x * 4;

    if (tid < 32) {
        int m = m0 + (tid >> 3);
        const float* lg = offlog + (size_t)m * 384 + 256 + (tid & 7) * 16;
        float w[16]; float mx = -1e30f;
#pragma unroll
        for (int i = 0; i < 4; ++i) {
            float4 v = reinterpret_cast<const float4*>(lg)[i];
            w[4 * i] = v.x; w[4 * i + 1] = v.y; w[4 * i + 2] = v.z; w[4 * i + 3] = v.w;
        }
#pragma unroll
        for (int j = 0; j < 16; ++j) mx = fmaxf(mx, w[j]);
        float s = 0.f;
#pragma unroll
        for (int j = 0; j < 16; ++j) { w[j] = __expf(w[j] - mx); s += w[j]; }
        float rs = 1.f / s;
#pragma unroll
        for (int j = 0; j < 16; ++j) aw_lds[tid][j] = w[j] * rs;
    }
    __syncthreads();

#pragma unroll
    for (int pp = 0; pp < 2; ++pp) {
        int pi = tid + 256 * pp;
        int qi = pi >> 7, rem = pi & 127;
        int h = rem >> 4, j = rem & 15;
        int l = j >> 2;
        int m = m0 + qi;
        int b = m / QTOT, q = m - b * QTOT;
        int lq = (q < 4096) ? 0 : (q < 5120) ? 1 : (q < 5376) ? 2 : 3;
        int qbase = (lq == 0) ? 0 : (lq == 1) ? 4096 : (lq == 2) ? 5120 : 5376;
        int qrem = q - qbase;
        int shq = 6 - lq;
        int Wq = 1 << shq;
        int yq = qrem >> shq, xq = qrem & (Wq - 1);
        float invq = 1.0f / (float)Wq;
        float ref_x = (xq + 0.5f) * invq;
        float ref_y = (yq + 0.5f) * invq;
        int HW = 64 >> l;
        float fHW = (float)HW;
        float invl = 1.0f / fHW;
        int loff = (l == 0) ? 0 : (l == 1) ? 4096 : (l == 2) ? 5120 : 5376;
        float ox = offlog[(size_t)m * 384 + h * 32 + j * 2 + 0];
        float oy = offlog[(size_t)m * 384 + h * 32 + j * 2 + 1];
        float aw = aw_lds[qi * 8 + h][j];
        float x = (ref_x + ox * invl) * fHW - 0.5f;
        float y = (ref_y + oy * invl) * fHW - 0.5f;
        float x0f = floorf(x), y0f = floorf(y);
        int x0 = (int)x0f, y0 = (int)y0f;
        float wx = x - x0f, wy = y - y0f;
        float vx0 = (x0 >= 0 && x0 < HW) ? 1.f : 0.f;
        float vx1 = (x0 + 1 >= 0 && x0 + 1 < HW) ? 1.f : 0.f;
        float vy0 = (y0 >= 0 && y0 < HW) ? 1.f : 0.f;
        float vy1 = (y0 + 1 >= 0 && y0 + 1 < HW) ? 1.f : 0.f;
        float w00 = (1.f - wx) * (1.f - wy) * aw * vx0 * vy0;
        float w01 = wx * (1.f - wy) * aw * vx1 * vy0;
        float w10 = (1.f - wx) * wy * aw * vx0 * vy1;
        float w11 = wx * wy * aw * vx1 * vy1;
        int xc0 = min(max(x0, 0), HW - 1);
        int xc1 = min(max(x0 + 1, 0), HW - 1);
        int yc0 = min(max(y0, 0), HW - 1);
        int yc1 = min(max(y0 + 1, 0), HW - 1);
        int rbase = b * QTOT + loff;
        int i00 = (rbase + yc0 * HW + xc0) << 10;
        int i01 = (rbase + yc0 * HW + xc1) << 10;
        int i10 = (rbase + yc1 * HW + xc0) << 10;
        int i11 = (rbase + yc1 * HW + xc1) << 10;
        int sl = (qi * 8 + h) * 17 + j;
        reinterpret_cast<float4*>(wts)[sl] = make_float4(w00, w01, w10, w11);
        reinterpret_cast<int4*>(idxs)[sl] = make_int4(i00, i01, i10, i11);
    }
    __syncthreads();

    int lane = tid & 63;
    int qi = tid >> 6, h = lane >> 3, c8 = lane & 7;
    int m = m0 + qi;
    const char* vb = (const char*)value + h * 128 + c8 * 16;
    int base = (qi * 8 + h) * 17;
    float a0 = 0.f, a1 = 0.f, a2 = 0.f, a3 = 0.f;
    float b0 = 0.f, b1 = 0.f, b2 = 0.f, b3 = 0.f;
#pragma unroll
    for (int j = 0; j < 16; j += 2) {
        float4 w0 = reinterpret_cast<const float4*>(wts)[base + j];
        int4  x0 = reinterpret_cast<const int4*>(idxs)[base + j];
        float4 w1 = reinterpret_cast<const float4*>(wts)[base + j + 1];
        int4  x1 = reinterpret_cast<const int4*>(idxs)[base + j + 1];
        float4 v00 = *reinterpret_cast<const float4*>(vb + x0.x);
        float4 v01 = *reinterpret_cast<const float4*>(vb + x0.y);
        float4 v10 = *reinterpret_cast<const float4*>(vb + x0.z);
        float4 v11 = *reinterpret_cast<const float4*>(vb + x0.w);
        float4 u00 = *reinterpret_cast<const float4*>(vb + x1.x);
        float4 u01 = *reinterpret_cast<const float4*>(vb + x1.y);
        float4 u10 = *reinterpret_cast<const float4*>(vb + x1.z);
        float4 u11 = *reinterpret_cast<const float4*>(vb + x1.w);
        a0 += w0.x * v00.x + w0.y * v01.x + w0.z * v10.x + w0.w * v11.x;
        a1 += w0.x * v00.y + w0.y * v01.y + w0.z * v10.y + w0.w * v11.y;
        a2 += w0.x * v00.z + w0.y * v01.z + w0.z * v10.z + w0.w * v11.z;
        a3 += w0.x * v00.w + w0.y * v01.w + w0.z * v10.w + w0.w * v11.w;
        b0 += w1.x * u00.x + w1.y * u01.x + w1.z * u10.x + w1.w * u11.x;
        b1 += w1.x * u00.y + w1.y * u01.y + w1.z * u10.y + w1.w * u11.y;
        b2 += w1.x * u00.z + w1.y * u01.z + w1.z * u10.z + w1.w * u11.z;
        b3 += w1.x * u00.w + w1.y * u01.w + w1.z * u10.w + w1.w * u11.w;
    }
    a0 += b0; a1 += b1; a2 += b2; a3 += b3;
    size_t oidx = (size_t)m * D_MODEL + h * 32 + c8 * 4;
    ushort4 hv, lv;
    hv.x = f2bf(a0); lv.x = f2bf(a0 - bf2f(hv.x));
    hv.y = f2bf(a1); lv.y = f2bf(a1 - bf2f(hv.y));
    hv.z = f2bf(a2); lv.z = f2bf(a2 - bf2f(hv.z));
    hv.w = f2bf(a3); lv.w = f2bf(a3 - bf2f(hv.w));
    *reinterpret_cast<ushort4*>(eh + oidx) = hv;
    *reinterpret_cast<ushort4*>(el + oidx) = lv;
}

// ---------------------------------------------------------------------------
// add+LN on pair-stored residual (4 rows/block, wave per row).
// TMODE 0: t fp32.  TMODE 1: t bf16 pair (th, tl).
// WRITEQ: also q = y + posf -> qh/ql.  WRITEF32: y -> f32out.
// ---------------------------------------------------------------------------
template<int TMODE, int WRITEQ, int WRITEF32>
__global__ __launch_bounds__(256) void add_ln_pair(
    const float* __restrict__ t, const u16* __restrict__ th,
    const u16* __restrict__ tl,
    const float* __restrict__ g, const float* __restrict__ beta,
    u16* __restrict__ oh, u16* __restrict__ ol,
    const float* __restrict__ posf, u16* __restrict__ qh, u16* __restrict__ ql,
    float* __restrict__ f32out)
{
    int row = blockIdx.x * 4 + (threadIdx.x >> 6);
    int lane = threadIdx.x & 63;
    size_t base = (size_t)row * D_MODEL + lane * 4;
    ushort4 hv = *reinterpret_cast<const ushort4*>(oh + base);
    ushort4 lv = *reinterpret_cast<const ushort4*>(ol + base);
    float t0, t1, t2, t3;
    if (TMODE == 0) {
        float4 tv = *reinterpret_cast<const float4*>(t + base);
        t0 = tv.x; t1 = tv.y; t2 = tv.z; t3 = tv.w;
    } else {
        ushort4 thv = *reinterpret_cast<const ushort4*>(th + base);
        ushort4 tlv = *reinterpret_cast<const ushort4*>(tl + base);
        t0 = bf2f(thv.x) + bf2f(tlv.x);
        t1 = bf2f(thv.y) + bf2f(tlv.y);
        t2 = bf2f(thv.z) + bf2f(tlv.z);
        t3 = bf2f(thv.w) + bf2f(tlv.w);
    }
    float v0 = bf2f(hv.x) + bf2f(lv.x) + t0;
    float v1 = bf2f(hv.y) + bf2f(lv.y) + t1;
    float v2 = bf2f(hv.z) + bf2f(lv.z) + t2;
    float v3 = bf2f(hv.w) + bf2f(lv.w) + t3;
    float s = v0 + v1 + v2 + v3;
#pragma unroll
    for (int o = 32; o > 0; o >>= 1) s += __shfl_xor(s, o);
    float mean = s * (1.f / D_MODEL);
    float d0 = v0 - mean, d1 = v1 - mean, d2 = v2 - mean, d3 = v3 - mean;
    float ss = d0 * d0 + d1 * d1 + d2 * d2 + d3 * d3;
#pragma unroll
    for (int o = 32; o > 0; o >>= 1) ss += __shfl_xor(ss, o);
    float rstd = rsqrtf(ss * (1.f / D_MODEL) + 1e-5f);
    float4 gv = *reinterpret_cast<const float4*>(&g[lane * 4]);
    float4 bv = *reinterpret_cast<const float4*>(&beta[lane * 4]);
    float y0 = d0 * rstd * gv.x + bv.x;
    float y1 = d1 * rstd * gv.y + bv.y;
    float y2 = d2 * rstd * gv.z + bv.z;
    float y3 = d3 * rstd * gv.w + bv.w;
    ushort4 nh, nl;
    nh.x = f2bf(y0); nl.x = f2bf(y0 - bf2f(nh.x));
    nh.y = f2bf(y1); nl.y = f2bf(y1 - bf2f(nh.y));
    nh.z = f2bf(y2); nl.z = f2bf(y2 - bf2f(nh.z));
    nh.w = f2bf(y3); nl.w = f2bf(y3 - bf2f(nh.w));
    *reinterpret_cast<ushort4*>(oh + base) = nh;
    *reinterpret_cast<ushort4*>(ol + base) = nl;
    if (WRITEQ) {
        float4 pv = *reinterpret_cast<const float4*>(posf + base);
        float q0 = y0 + pv.x, q1 = y1 + pv.y, q2 = y2 + pv.z, q3 = y3 + pv.w;
        ushort4 qhv, qlv;
        qhv.x = f2bf(q0); qlv.x = f2bf(q0 - bf2f(qhv.x));
        qhv.y = f2bf(q1); qlv.y = f2bf(q1 - bf2f(qhv.y));
        qhv.z = f2bf(q2); qlv.z = f2bf(q2 - bf2f(qhv.z));
        qhv.w = f2bf(q3); qlv.w = f2bf(q3 - bf2f(qhv.w));
        *reinterpret_cast<ushort4*>(qh + base) = qhv;
        *reinterpret_cast<ushort4*>(ql + base) = qlv;
    }
    if (WRITEF32) {
        *reinterpret_cast<float4*>(f32out + base) = make_float4(y0, y1, y2, y3);
    }
}

// ---------------------------------------------------------------------------
extern "C" void kernel_launch(void* const* d_in, const int* in_sizes, int n_in,
                              void* d_out, int out_size, void* d_ws, size_t ws_size,
                              hipStream_t stream)
{
    // dict order is INTERLEAVED: src0,pos0,src1,pos1,...
    const float* src[4] = {(const float*)d_in[0], (const float*)d_in[2],
                           (const float*)d_in[4], (const float*)d_in[6]};
    const float* pos[4] = {(const float*)d_in[1], (const float*)d_in[3],
                           (const float*)d_in[5], (const float*)d_in[7]};
    const float* lvl   = (const float*)d_in[8];
    const float* W_off = (const float*)d_in[9];
    const float* b_off = (const float*)d_in[10];
    const float* W_att = (const float*)d_in[11];
    const float* b_att = (const float*)d_in[12];
    const float* W_val = (const float*)d_in[13];
    const float* b_val = (const float*)d_in[14];
    const float* W_out = (const float*)d_in[15];
    const float* b_out = (const float*)d_in[16];
    const float* ln1g  = (const float*)d_in[17];
    const float* ln1b  = (const float*)d_in[18];
    const float* W_ff1 = (const float*)d_in[19];
    const float* b_ff1 = (const float*)d_in[20];
    const float* W_ff2 = (const float*)d_in[21];
    const float* b_ff2 = (const float*)d_in[22];
    const float* ln2g  = (const float*)d_in[23];
    const float* ln2b  = (const float*)d_in[24];

    float* ws = (float*)d_ws;
    const size_t MD = (size_t)MTOT * D_MODEL;    // 5,570,560

    // Workspace layout (~140.6 MB; proven to fit in rounds 4-16):
    float* posf = ws;                                    // fp32 [M,256]
    u16* oh = (u16*)(ws + MD);
    u16* ol = oh + MD;
    u16* qh = ol + MD;                                   // q / e / ff2-out pair
    u16* ql = qh + MD;
    u16* eh = qh; u16* el = ql;
    float* val    = (float*)(ql + MD);                   // fp32 [M,256]
    float* offlog = val + MD;                            // fp32 [M,384]; tmp
    float* tmp    = offlog;
    u16* hid = (u16*)val;   // FFN hidden, SINGLE bf16, full M: [M,1024]=44.6MB
    u16* wb = (u16*)(offlog + (size_t)MTOT * 384);
    size_t o = 0;
    u16* wv_h = wb + o; o += 6 * 65536;  u16* wv_l = wb + o; o += 6 * 65536;
    u16* wc_h = wb + o; o += 6 * 98304;  u16* wc_l = wb + o; o += 6 * 98304;
    u16* wu_h = wb + o; o += 6 * 65536;  u16* wu_l = wb + o; o += 6 * 65536;
    u16* wf1_h = wb + o; o += 6 * 262144; u16* wf1_l = wb + o; o += 6 * 262144;
    u16* wf2_h = wb + o; o += 6 * 262144; u16* wf2_l = wb + o; o += 6 * 262144;

    dim3 cb(32, 8);
    flatten_all<<<dim3(170, 8, BATCH), cb, 0, stream>>>(
        src[0], src[1], src[2], src[3], pos[0], pos[1], pos[2], pos[3],
        lvl, posf, oh, ol, qh, ql);
    wconv_all<<<6 * 736, cb, 0, stream>>>(
        W_val, W_off, W_att, W_out, W_ff1, W_ff2,
        wv_h, wv_l, wc_h, wc_l, wu_h, wu_l, wf1_h, wf1_l, wf2_h, wf2_l);

    for (int i = 0; i < NLAYER; ++i) {
        gemm_vo<<<850, 256, 0, stream>>>(
            oh, ol, qh, ql,
            wv_h + i * 65536, wv_l + i * 65536,
            wc_h + i * 98304, wc_l + i * 98304,
            b_val + i * 256, b_off + i * 256, b_att + i * 128,
            val, offlog);
        msda3<<<MTOT / 4, 256, 0, stream>>>(val, offlog, eh, el);
        gemm_pre<0, 1><<<340, 256, 0, stream>>>(
            eh, el, wu_h + i * 65536, wu_l + i * 65536,
            b_out + i * 256, b_out + i * 256, 256,
            tmp, nullptr, nullptr, 256, 256, 2);
        add_ln_pair<0, 0, 0><<<MTOT / 4, 256, 0, stream>>>(
            tmp, nullptr, nullptr, ln1g + i * 256, ln1b + i * 256, oh, ol,
            nullptr, nullptr, nullptr, nullptr);
        // FFN full-M: ff1 -> single-bf16 hidden; ff2 2-pass (no A-lo).
        gemm_pre<3, 1><<<1360, 256, 0, stream>>>(
            oh, ol, wf1_h + i * 262144, wf1_l + i * 262144,
            b_ff1 + i * 1024, b_ff1 + i * 1024, 1024,
            nullptr, hid, nullptr, 1024, 256, 8);
        gemm_pre<2, 0><<<340, 256, 0, stream>>>(
            hid, nullptr, wf2_h + i * 262144, wf2_l + i * 262144,
            b_ff2 + i * 256, b_ff2 + i * 256, 256,
            nullptr, eh, el, 256, 1024, 2);
        if (i < NLAYER - 1)
            add_ln_pair<1, 1, 0><<<MTOT / 4, 256, 0, stream>>>(
                nullptr, eh, el, ln2g + i * 256, ln2b + i * 256, oh, ol,
                posf, qh, ql, nullptr);
        else
            add_ln_pair<1, 0, 1><<<MTOT / 4, 256, 0, stream>>>(
                nullptr, eh, el, ln2g + i * 256, ln2b + i * 256, oh, ol,
                nullptr, nullptr, nullptr, (float*)d_out);
    }
    (void)in_sizes; (void)n_in; (void)out_size; (void)ws_size;
}